// Round 19
// baseline (763.174 us; speedup 1.0000x reference)
//
#include <hip/hip_runtime.h>

// ---------------------------------------------------------------------------
// ROUND 19: fused energy+PV (no-softmax flash style) on green r18 (479us).
// Per block = one (slice nh, 64-row q-tile): loop 8 l-tiles {
//   S=Q.K_l^T (K=512, waves split l-frags) -> mask+f2b -> S-LDS[64][136]
//   -> O += S.V_l (A-frags from S-LDS, V direct global->VGPR, L2-pinned) }
// O (128 f32 regs/lane) -> per-head bf16 out; reduce8 sums heads.
// Kills the P round-trip (128MB/iter) and Ah partials. 11 dispatches.
// Kept from r18: convw4, maskbits, conv3, proj3 (MODE 6), final (MODE 5),
// full-tile repack epilogues, all validated index maps.
// ---------------------------------------------------------------------------

#define RS 0.04419417382415922f  // 1/sqrt(512)

typedef __attribute__((ext_vector_type(8))) short bf16x8;
typedef __attribute__((ext_vector_type(4))) float f32x4;

__device__ __forceinline__ unsigned short f2b(float f) {
  unsigned u = __builtin_bit_cast(unsigned, f);
  unsigned r = (u + 0x7FFFu + ((u >> 16) & 1u)) >> 16;  // RNE
  return (unsigned short)r;
}
__device__ __forceinline__ float b2f(unsigned short h) {
  return __builtin_bit_cast(float, ((unsigned)h) << 16);
}

__global__ void k_fill(float* p, int n, float v) {
  int i = blockIdx.x * blockDim.x + threadIdx.x;
  int stride = gridDim.x * blockDim.x;
  for (; i < n; i += stride) p[i] = v;
}

__global__ void k_maskbits(const int* __restrict__ m,
                           unsigned* __restrict__ bits) {
  int wi = blockIdx.x * 256 + threadIdx.x;
  const int* src = m + (size_t)wi * 32;
  unsigned b = 0;
#pragma unroll
  for (int i = 0; i < 32; ++i) b |= (src[i] != 0 ? 1u : 0u) << i;
  bits[wi] = b;
}

// all 4 weight tensors; z: 0=Wv,1=Wk,2=Wq(xRS),3=Wo
__global__ void k_convw4(const float4* __restrict__ wv,
                         const float4* __restrict__ wk,
                         const float4* __restrict__ wq,
                         const float4* __restrict__ wo,
                         ushort4* __restrict__ dqkv, ushort4* __restrict__ dwo) {
  int z = blockIdx.z;
  const float4* s = (z == 0) ? wv : (z == 1) ? wk : (z == 2) ? wq : wo;
  ushort4* d = (z == 3) ? dwo : dqkv + (size_t)z * 524288;
  int n4 = (z == 3) ? 65536 : 524288;
  float scale = (z == 2) ? RS : 1.0f;
  int stride = gridDim.x * blockDim.x;
  for (int i = blockIdx.x * blockDim.x + threadIdx.x; i < n4; i += stride) {
    float4 v = s[i];
    ushort4 o;
    o.x = f2b(v.x * scale); o.y = f2b(v.y * scale);
    o.z = f2b(v.z * scale); o.w = f2b(v.w * scale);
    d[i] = o;
  }
}

__global__ void k_conv3(const float4* __restrict__ v,
                        const float4* __restrict__ k,
                        const float4* __restrict__ q, ushort4* __restrict__ d,
                        int n4, int dstride) {
  const float4* s = (blockIdx.z == 0) ? v : (blockIdx.z == 1) ? k : q;
  ushort4* dz = d + (size_t)blockIdx.z * dstride;
  int stride = gridDim.x * blockDim.x;
  for (int i = blockIdx.x * blockDim.x + threadIdx.x; i < n4; i += stride) {
    float4 x = s[i];
    ushort4 o;
    o.x = f2b(x.x); o.y = f2b(x.y); o.z = f2b(x.z); o.w = f2b(x.w);
    dz[i] = o;
  }
}

// Sum 8 head-slices per n: a=[nl*8+h][1024][512] bf16 -> o[nl][1024*512]
__global__ void k_reduce8(const unsigned short* __restrict__ a,
                          unsigned short* __restrict__ o, int total) {
  int i = blockIdx.x * blockDim.x + threadIdx.x;
  if (i >= total) return;
  int nl = i >> 17, j = i & 131071;
  const ushort4* av = (const ushort4*)a + (size_t)nl * 1048576;
  float4 s = {0.f, 0.f, 0.f, 0.f};
#pragma unroll
  for (int h = 0; h < 8; ++h) {
    ushort4 v = av[h * 131072 + j];
    s.x += b2f(v.x); s.y += b2f(v.y); s.z += b2f(v.z); s.w += b2f(v.w);
  }
  ushort4 r;
  r.x = f2b(s.x); r.y = f2b(s.y); r.z = f2b(s.z); r.w = f2b(s.w);
  ((ushort4*)o)[i] = r;
}

#define GLD16(gp, sp)                                              \
  __builtin_amdgcn_global_load_lds(                                \
      (const __attribute__((address_space(1))) void*)(gp),         \
      (__attribute__((address_space(3))) void*)(sp), 16, 0, 0)

// ---------------- fused energy+PV ----------------
// grid (NSLICE, 16): bz = slice (z-major, XCD-pinned), qt = q-tile of 64.
// Waves: energy S[64q][l: wid*32+32) ; PV O[64q][e: wid*128+128).
__global__ __launch_bounds__(256) void k_fused(
    const unsigned short* __restrict__ Qb, const unsigned short* __restrict__ Kb,
    const unsigned short* __restrict__ VTb, const unsigned* __restrict__ mbits,
    unsigned short* __restrict__ Ob, int n0) {
  // bytes: A dbuf [0,8192), B dbuf [8192,24576), S 64x136 [24576,41984)
  __shared__ short smem[20992];
  short* const Ss = smem + 12288;

  const int tid = threadIdx.x;
  const int wid = tid >> 6, lane = tid & 63;
  const int l15 = lane & 15, l4 = lane >> 4;
  const int bz = blockIdx.x, qt = blockIdx.y;

  const unsigned short* Qt = Qb + (size_t)bz * 524288 + (size_t)qt * 64 * 512;
  const unsigned short* Kh = Kb + (size_t)bz * 524288;
  const unsigned short* Vh = VTb + (size_t)bz * 524288;
  const int n = n0 + (bz >> 3);

  f32x4 accO[4][8];
#pragma unroll
  for (int f = 0; f < 4; ++f)
#pragma unroll
    for (int e = 0; e < 8; ++e) accO[f][e] = (f32x4){0.f, 0.f, 0.f, 0.f};

#define STGF(buf, kc)                                                      \
  {                                                                        \
    int cA = wid * 64 + lane;                                              \
    GLD16(Qt + (size_t)(cA >> 2) * 512 + (kc)*32 + ((cA & 3) << 3),        \
          (char*)smem + (buf)*4096 + wid * 1024);                          \
    _Pragma("unroll") for (int is = 0; is < 2; ++is) {                     \
      int cB = is * 256 + tid;                                             \
      GLD16(Kl + (size_t)(cB >> 2) * 512 + (kc)*32 + ((cB & 3) << 3),      \
            (char*)smem + 8192 + (buf)*8192 + is * 4096 + wid * 1024);     \
    }                                                                      \
  }

  for (int lt = 0; lt < 8; ++lt) {
    const unsigned short* Kl = Kh + (size_t)lt * 128 * 512;
    f32x4 accS[4][2];
#pragma unroll
    for (int f = 0; f < 4; ++f) {
      accS[f][0] = (f32x4){0.f, 0.f, 0.f, 0.f};
      accS[f][1] = (f32x4){0.f, 0.f, 0.f, 0.f};
    }

    STGF(0, 0);
    int cur = 0;
#pragma unroll 4
    for (int kc = 0; kc < 16; ++kc) {
      __syncthreads();  // drains vmcnt: buf[cur] staged; prior reads done
      if (kc + 1 < 16) STGF(cur ^ 1, kc + 1);
      bf16x8 aq[4], bk[2];
#pragma unroll
      for (int f = 0; f < 4; ++f)
        aq[f] = *(const bf16x8*)((char*)smem + cur * 4096 +
                                 ((f * 16 + l15) << 6) + (l4 << 4));
#pragma unroll
      for (int g = 0; g < 2; ++g)
        bk[g] = *(const bf16x8*)((char*)smem + 8192 + cur * 8192 +
                                 ((wid * 32 + g * 16 + l15) << 6) + (l4 << 4));
#pragma unroll
      for (int f = 0; f < 4; ++f)
#pragma unroll
        for (int g = 0; g < 2; ++g)
          accS[f][g] = __builtin_amdgcn_mfma_f32_16x16x32_bf16(
              aq[f], bk[g], accS[f][g], 0, 0, 0);
      cur ^= 1;
    }

    // repack S (mask + f2b); own-wave region only, then barrier for PV
#pragma unroll
    for (int f = 0; f < 4; ++f)
#pragma unroll
      for (int g = 0; g < 2; ++g)
#pragma unroll
        for (int r = 0; r < 4; ++r) {
          int q_loc = f * 16 + l4 * 4 + r;
          int l_loc = wid * 32 + g * 16 + l15;
          int l_glob = lt * 128 + l_loc;
          int q_glob = qt * 64 + q_loc;
          unsigned mw =
              mbits[((size_t)n * 1024 + q_glob) * 32 + (l_glob >> 5)];
          Ss[q_loc * 136 + l_loc] =
              ((mw >> (l_glob & 31)) & 1u)
                  ? (short)f2b(accS[f][g][r])
                  : (short)0;
        }
    __syncthreads();

    // PV: O += S @ V_l ; A from S-LDS, B direct global (L2-pinned slice)
#pragma unroll
    for (int ks = 0; ks < 4; ++ks) {
      bf16x8 as_[4];
#pragma unroll
      for (int f = 0; f < 4; ++f)
        as_[f] = *(const bf16x8*)(Ss + (f * 16 + l15) * 136 + ks * 32 + l4 * 8);
#pragma unroll
      for (int fe = 0; fe < 8; ++fe) {
        bf16x8 bv = *(const bf16x8*)(Vh +
                                     (size_t)(wid * 128 + fe * 16 + l15) * 1024 +
                                     lt * 128 + ks * 32 + l4 * 8);
#pragma unroll
        for (int f = 0; f < 4; ++f)
          accO[f][fe] = __builtin_amdgcn_mfma_f32_16x16x32_bf16(
              as_[f], bv, accO[f][fe], 0, 0, 0);
      }
    }
    __syncthreads();  // PV reads of Ss done before next repack overwrites
  }
#undef STGF

  // ---- O epilogue: two 256-col passes via Cs[64][264] (smem reuse) ----
#pragma unroll
  for (int p = 0; p < 2; ++p) {
    __syncthreads();
    if ((wid >> 1) == p) {
#pragma unroll
      for (int f = 0; f < 4; ++f)
#pragma unroll
        for (int fe = 0; fe < 8; ++fe)
#pragma unroll
          for (int r = 0; r < 4; ++r) {
            int row = f * 16 + l4 * 4 + r;
            int col = (wid & 1) * 128 + fe * 16 + l15;
            smem[row * 264 + col] = (short)f2b(accO[f][fe][r]);
          }
    }
    __syncthreads();
#pragma unroll
    for (int ch = 0; ch < 8; ++ch) {
      int idx = ch * 256 + tid;
      int row = idx >> 5;
      int col = (idx & 31) << 3;
      *(bf16x8*)(Ob + (size_t)bz * 524288 + (size_t)(qt * 64 + row) * 512 +
                 p * 256 + col) = *(const bf16x8*)(smem + row * 264 + col);
    }
  }
}

// ---------------- GEMM (proj3 + final), r18-validated ----------------
// MODE 5: final->fp32 (+bias bi0). MODE 6: proj3 (z: 0=VT,1=K,2=Q).
template <int MODE>
__global__ __launch_bounds__(256) void k_gemm(
    const unsigned short* __restrict__ A, const unsigned short* __restrict__ B,
    const float* __restrict__ bi0, const float* __restrict__ bi1,
    const float* __restrict__ bi2, unsigned short* __restrict__ outb,
    float* __restrict__ outf, int xstr, int ostr) {
  __shared__ short smem[17408];
  char* const sb = (char*)smem;

  const int tid = threadIdx.x;
  const int wid = tid >> 6;
  const int lane = tid & 63;
  const int wr = wid >> 1, wc = wid & 1;
  const int l15 = lane & 15, l4 = lane >> 4;
  const int bx = blockIdx.x, by = blockIdx.y, bz = blockIdx.z;

  f32x4 acc[4][4];
#pragma unroll
  for (int i = 0; i < 4; ++i)
#pragma unroll
    for (int j = 0; j < 4; ++j) acc[i][j] = (f32x4){0.f, 0.f, 0.f, 0.f};

  const unsigned short* Ab;
  const unsigned short* Bb;
  if constexpr (MODE == 5) {
    Ab = A + (size_t)bx * 128 * 512;
    Bb = B + (size_t)by * 128 * 512;
  } else {
    Ab = A + (size_t)bz * xstr + (size_t)bx * 128 * 512;
    Bb = B + (size_t)bz * 2097152 + (size_t)by * 128 * 512;
  }

#define STAGE(buf, kc)                                             \
  {                                                                \
    _Pragma("unroll") for (int is = 0; is < 2; ++is) {             \
      int c = is * 256 + tid;                                      \
      int row = c >> 2, col = (c & 3) << 3;                        \
      GLD16(Ab + (size_t)row * 512 + (kc)*32 + col,                \
            sb + (buf)*8192 + is * 4096 + wid * 1024);             \
      GLD16(Bb + (size_t)row * 512 + (kc)*32 + col,                \
            sb + 16384 + (buf)*8192 + is * 4096 + wid * 1024);     \
    }                                                              \
  }

  STAGE(0, 0);
  int cur = 0;
#pragma unroll 4
  for (int kc = 0; kc < 16; ++kc) {
    __syncthreads();
    if (kc + 1 < 16) STAGE(cur ^ 1, kc + 1);
    bf16x8 af[4], bf_[4];
#pragma unroll
    for (int f = 0; f < 4; ++f) {
      af[f] = *(const bf16x8*)(sb + cur * 8192 +
                               ((wr * 64 + f * 16 + l15) << 6) + (l4 << 4));
      bf_[f] = *(const bf16x8*)(sb + 16384 + cur * 8192 +
                                ((wc * 64 + f * 16 + l15) << 6) + (l4 << 4));
    }
#pragma unroll
    for (int mf = 0; mf < 4; ++mf)
#pragma unroll
      for (int nf = 0; nf < 4; ++nf)
        acc[mf][nf] = __builtin_amdgcn_mfma_f32_16x16x32_bf16(
            af[mf], bf_[nf], acc[mf][nf], 0, 0, 0);
    cur ^= 1;
  }
#undef STAGE

  const int r0 = l4 * 4;
  const int c0 = l15;

  if constexpr (MODE == 6) {
    const bool transp = (bz == 0);  // VT tile
    const float* bias = (bz == 0) ? bi0 : (bz == 1) ? bi1 : bi2;
    const float bscale = (bz == 2) ? RS : 1.0f;
    __syncthreads();
#pragma unroll
    for (int nf = 0; nf < 4; ++nf) {
      int c_loc = wc * 64 + nf * 16 + c0;
      float bvl = bias[by * 128 + c_loc] * bscale;
#pragma unroll
      for (int mf = 0; mf < 4; ++mf)
#pragma unroll
        for (int r = 0; r < 4; ++r) {
          int r_loc = wr * 64 + mf * 16 + r0 + r;
          unsigned short bb = f2b(acc[mf][nf][r] + bvl);
          if (transp)
            smem[c_loc * 136 + r_loc] = (short)bb;
          else
            smem[r_loc * 136 + c_loc] = (short)bb;
        }
    }
    __syncthreads();
#pragma unroll
    for (int ch = 0; ch < 8; ++ch) {
      int idx = ch * 256 + tid;
      int row = idx >> 4;
      int col = (idx & 15) << 3;
      bf16x8 v = *(const bf16x8*)(smem + row * 136 + col);
      unsigned short* O = outb + (size_t)bz * ostr;
      if (bz == 0) {  // VT [nl][h][e][s]; tile rows = e-dim
        int eB = by * 128 + row;
        int r_ = bx * 128 + col;
        int nl = r_ >> 10, s = r_ & 1023, h = eB >> 9, e = eB & 511;
        *(bf16x8*)(O + (((size_t)nl * 8 + h) * 512 + e) * 1024 + s) = v;
      } else {  // K/Q [nl][h][s][e]
        int r_ = bx * 128 + row, cB = by * 128 + col;
        int nl = r_ >> 10, s = r_ & 1023, h = cB >> 9, e = cB & 511;
        *(bf16x8*)(O + (((size_t)nl * 8 + h) * 1024 + s) * 512 + e) = v;
      }
    }
  } else {  // MODE 5: fp32, two 64-row passes via Cs32[64][136]
    float* const Cs32 = (float*)smem;
#pragma unroll
    for (int hh = 0; hh < 2; ++hh) {
      __syncthreads();
      if (wr == hh) {
#pragma unroll
        for (int nf = 0; nf < 4; ++nf) {
          int c_loc = wc * 64 + nf * 16 + c0;
          float bvl = bi0[by * 128 + c_loc];
#pragma unroll
          for (int mf = 0; mf < 4; ++mf)
#pragma unroll
            for (int r = 0; r < 4; ++r)
              Cs32[(mf * 16 + r0 + r) * 136 + c_loc] = acc[mf][nf][r] + bvl;
        }
      }
      __syncthreads();
#pragma unroll
      for (int ch = 0; ch < 8; ++ch) {
        int idx = ch * 256 + tid;
        int row = idx >> 5;
        int col = (idx & 31) << 2;
        float4 v = *(const float4*)(Cs32 + row * 136 + col);
        *(float4*)(outf + (size_t)(bx * 128 + hh * 64 + row) * 512 +
                   by * 128 + col) = v;
      }
    }
  }
}

extern "C" void kernel_launch(void* const* d_in, const int* in_sizes, int n_in,
                              void* d_out, int out_size, void* d_ws,
                              size_t ws_size, hipStream_t stream) {
  const float* values = (const float*)d_in[0];
  const float* keys = (const float*)d_in[1];
  const float* query = (const float*)d_in[2];
  const int* maskI = (const int*)d_in[4];
  const float* Wv = (const float*)d_in[5];
  const float* bv = (const float*)d_in[6];
  const float* Wk = (const float*)d_in[7];
  const float* bk = (const float*)d_in[8];
  const float* Wq = (const float*)d_in[9];
  const float* bq = (const float*)d_in[10];
  const float* Wo = (const float*)d_in[11];
  const float* bo = (const float*)d_in[12];
  float* dout = (float*)d_out;

  const int exp_sizes[13] = {4194304, 4194304, 4194304, 1024, 8388608,
                             2097152, 4096,    2097152, 4096, 2097152,
                             4096,    262144,  512};
  bool ok = (n_in == 13);
  if (ok)
    for (int i = 0; i < 13; ++i)
      if (in_sizes[i] != exp_sizes[i]) ok = false;
  if (!ok) {
    k_fill<<<512, 256, 0, stream>>>(dout, out_size, 1000.f);
    return;
  }

  // ---- workspace (BYTES): W | Wo | Atb | mbits | VT | K | Q | P/O ----
  const size_t SZT2 = 16777216, SZT4 = 33554432;
  const size_t need2 = 22544384 + 3 * SZT2 + 2 * SZT2;  // 106,430,464
  const size_t need4 = 22544384 + 3 * SZT4 + 2 * SZT4;  // 190,316,544
  const int NL = (ws_size >= need4) ? 4 : 2;
  if (ws_size < need2) {
    k_fill<<<512, 256, 0, stream>>>(dout, out_size, 2000.f);
    return;
  }
  const size_t SZT = (size_t)NL * 8388608;

  char* w = (char*)d_ws;
  unsigned short* Wvb = (unsigned short*)(w);             // 3 x 4,194,304
  unsigned short* Wob = (unsigned short*)(w + 12582912);  //     524,288
  unsigned short* Atb = (unsigned short*)(w + 13107200);  //   8,388,608
  unsigned* mbits = (unsigned*)(w + 21495808);            //   1,048,576
  unsigned short* VTb = (unsigned short*)(w + 22544384);
  unsigned short* Kb = (unsigned short*)(w + 22544384 + SZT);
  unsigned short* Qb = (unsigned short*)(w + 22544384 + 2 * SZT);
  unsigned short* Pb = (unsigned short*)(w + 22544384 + 3 * SZT);
  unsigned short* Xc = (unsigned short*)Pb;  // conv out; dead before fused
  unsigned short* Ob = (unsigned short*)Pb;  // fused per-head output

  k_convw4<<<dim3(512, 1, 4), 256, 0, stream>>>(
      (const float4*)Wv, (const float4*)Wk, (const float4*)Wq,
      (const float4*)Wo, (ushort4*)Wvb, (ushort4*)Wob);
  k_maskbits<<<1024, 256, 0, stream>>>(maskI, mbits);

  const int xstr = NL * 524288;   // elems per tensor slice in Xc
  const int ostr = NL * 4194304;  // elems per output tensor (VT/K/Q)

  for (int it = 0; it < 8 / NL; ++it) {
    const int n0 = it * NL;
    const size_t xoff = (size_t)n0 * 524288;
    k_conv3<<<dim3(512 * NL, 1, 3), 256, 0, stream>>>(
        (const float4*)(values + xoff), (const float4*)(keys + xoff),
        (const float4*)(query + xoff), (ushort4*)Xc, NL * 131072, NL * 131072);
    // proj3: M=NL*1024, N=4096, K=512; z: 0=VT,1=K,2=Q
    k_gemm<6><<<dim3(NL * 8, 32, 3), 256, 0, stream>>>(
        Xc, Wvb, bv, bk, bq, VTb, nullptr, xstr, ostr);
    // fused energy+PV: slices = NL*8, q-tiles = 16
    k_fused<<<dim3(NL * 8, 16, 1), 256, 0, stream>>>(Qb, Kb, VTb, mbits, Ob,
                                                     n0);
    // head-sum -> Atb
    k_reduce8<<<NL * 512, 256, 0, stream>>>(Ob, Atb + (size_t)n0 * 524288,
                                            NL * 131072);
  }

  // ---- final: [8192][512] @ Wo^T + bo -> fp32 d_out ----
  k_gemm<5><<<dim3(64, 4, 1), 256, 0, stream>>>(Atb, Wob, bo, nullptr, nullptr,
                                                nullptr, dout, 0, 0);
}

// Round 20
// 489.342 us; speedup vs baseline: 1.5596x; 1.5596x over previous
//
#include <hip/hip_runtime.h>

// ---------------------------------------------------------------------------
// ROUND 20: REVERT r19 fusion (VGPR 240 -> 11% occupancy, 763us). Back to
// r18 (479us, best) + fold head-sum into final GEMM:
//   final MODE 5 NSEG=4: out = sum_g (Ah_g @ Wo^T) + bo  (linearity)
//   -> k_reduce4 deleted, Atb round-trip deleted; Ah persistent (32MB).
// Layout (BYTES): W(12.58M) | Wo(.5M) | Ahb(33.55M) | mbits(1M) | VT|K|Q|P.
// NL=4 tier = 215.5MB <= proven 222.8MB (r13 ran 222.8 guard).
// All else = r18: conv3, proj3 (MODE 6), energy (MODE 2, bitmask, z-major),
// PV (MODE 4, NSEG=2, z-major), dbuf GLD16 staging, full-tile repack epi.
// ---------------------------------------------------------------------------

#define RS 0.04419417382415922f  // 1/sqrt(512)

typedef __attribute__((ext_vector_type(8))) short bf16x8;
typedef __attribute__((ext_vector_type(4))) float f32x4;

__device__ __forceinline__ unsigned short f2b(float f) {
  unsigned u = __builtin_bit_cast(unsigned, f);
  unsigned r = (u + 0x7FFFu + ((u >> 16) & 1u)) >> 16;  // RNE
  return (unsigned short)r;
}
__device__ __forceinline__ float b2f(unsigned short h) {
  return __builtin_bit_cast(float, ((unsigned)h) << 16);
}

__global__ void k_fill(float* p, int n, float v) {
  int i = blockIdx.x * blockDim.x + threadIdx.x;
  int stride = gridDim.x * blockDim.x;
  for (; i < n; i += stride) p[i] = v;
}

__global__ void k_maskbits(const int* __restrict__ m,
                           unsigned* __restrict__ bits) {
  int wi = blockIdx.x * 256 + threadIdx.x;
  const int* src = m + (size_t)wi * 32;
  unsigned b = 0;
#pragma unroll
  for (int i = 0; i < 32; ++i) b |= (src[i] != 0 ? 1u : 0u) << i;
  bits[wi] = b;
}

// all 4 weight tensors; z: 0=Wv,1=Wk,2=Wq(xRS),3=Wo
__global__ void k_convw4(const float4* __restrict__ wv,
                         const float4* __restrict__ wk,
                         const float4* __restrict__ wq,
                         const float4* __restrict__ wo,
                         ushort4* __restrict__ dqkv, ushort4* __restrict__ dwo) {
  int z = blockIdx.z;
  const float4* s = (z == 0) ? wv : (z == 1) ? wk : (z == 2) ? wq : wo;
  ushort4* d = (z == 3) ? dwo : dqkv + (size_t)z * 524288;
  int n4 = (z == 3) ? 65536 : 524288;
  float scale = (z == 2) ? RS : 1.0f;
  int stride = gridDim.x * blockDim.x;
  for (int i = blockIdx.x * blockDim.x + threadIdx.x; i < n4; i += stride) {
    float4 v = s[i];
    ushort4 o;
    o.x = f2b(v.x * scale); o.y = f2b(v.y * scale);
    o.z = f2b(v.z * scale); o.w = f2b(v.w * scale);
    d[i] = o;
  }
}

// conv fp32->bf16 for v/k/q slices in one dispatch (z selects tensor).
__global__ void k_conv3(const float4* __restrict__ v,
                        const float4* __restrict__ k,
                        const float4* __restrict__ q, ushort4* __restrict__ d,
                        int n4, int dstride) {
  const float4* s = (blockIdx.z == 0) ? v : (blockIdx.z == 1) ? k : q;
  ushort4* dz = d + (size_t)blockIdx.z * dstride;
  int stride = gridDim.x * blockDim.x;
  for (int i = blockIdx.x * blockDim.x + threadIdx.x; i < n4; i += stride) {
    float4 x = s[i];
    ushort4 o;
    o.x = f2b(x.x); o.y = f2b(x.y); o.z = f2b(x.z); o.w = f2b(x.w);
    dz[i] = o;
  }
}

#define GLD16(gp, sp)                                              \
  __builtin_amdgcn_global_load_lds(                                \
      (const __attribute__((address_space(1))) void*)(gp),         \
      (__attribute__((address_space(3))) void*)(sp), 16, 0, 0)

// 128x128-tile GEMM, dbuf GLD16 staging, 1 barrier/K-step, full-tile
// LDS-repacked epilogue. smem = 17408 shorts (34.8KB).
// MODE 2: energy->P[z][q][l], bitmask; z-major (bz=blockIdx.x).
// MODE 4: PV 2-head in-reg sum -> Ah[z][q][e]; z=(n_l,g4), z-major, K=2x1024.
// MODE 5: final->fp32 (+bias bi0), NSEG=4 over g-partials of Ah.
// MODE 6: proj3 (z: 0=VT,1=K,2=Q).
template <int MODE>
__global__ __launch_bounds__(256) void k_gemm(
    const unsigned short* __restrict__ A, const unsigned short* __restrict__ B,
    const float* __restrict__ bi0, const float* __restrict__ bi1,
    const float* __restrict__ bi2, const unsigned* __restrict__ mbits,
    unsigned short* __restrict__ outb, float* __restrict__ outf, int n0,
    int xstr, int ostr) {
  __shared__ short smem[17408];
  char* const sb = (char*)smem;

  const int tid = threadIdx.x;
  const int wid = tid >> 6;
  const int lane = tid & 63;
  const int wr = wid >> 1, wc = wid & 1;
  const int l15 = lane & 15, l4 = lane >> 4;

  int bx, by, bz;
  if constexpr (MODE == 2 || MODE == 4) {  // z-major: XCD-pinned slices
    bz = blockIdx.x; bx = blockIdx.y; by = blockIdx.z;
  } else {
    bx = blockIdx.x; by = blockIdx.y; bz = blockIdx.z;
  }

  constexpr int KSEG = (MODE == 4) ? 1024 : 512;
  constexpr int NK = KSEG / 32;
  constexpr int NSEG = (MODE == 4) ? 2 : (MODE == 5) ? 4 : 1;

  f32x4 acc[4][4];
#pragma unroll
  for (int i = 0; i < 4; ++i)
#pragma unroll
    for (int j = 0; j < 4; ++j) acc[i][j] = (f32x4){0.f, 0.f, 0.f, 0.f};

  const unsigned short* Ab;
  const unsigned short* Bb;

#define STAGE(buf, kc)                                             \
  {                                                                \
    _Pragma("unroll") for (int is = 0; is < 2; ++is) {             \
      int c = is * 256 + tid;                                      \
      int row = c >> 2, col = (c & 3) << 3;                        \
      GLD16(Ab + (size_t)row * KSEG + (kc)*32 + col,               \
            sb + (buf)*8192 + is * 4096 + wid * 1024);             \
      GLD16(Bb + (size_t)row * KSEG + (kc)*32 + col,               \
            sb + 16384 + (buf)*8192 + is * 4096 + wid * 1024);     \
    }                                                              \
  }

  for (int seg = 0; seg < NSEG; ++seg) {
    if constexpr (MODE == 5) {  // A = Ah[(n*4+seg)]; n = bx>>3
      int n = bx >> 3;
      Ab = A + (size_t)(n * 4 + seg) * 524288 + (size_t)(bx & 7) * 128 * 512;
      Bb = B + (size_t)by * 128 * 512;
    } else if constexpr (MODE == 6) {
      Ab = A + (size_t)bz * xstr + (size_t)bx * 128 * 512;
      Bb = B + (size_t)bz * 2097152 + (size_t)by * 128 * 512;
    } else if constexpr (MODE == 2) {
      Ab = A + (size_t)bz * 524288 + (size_t)bx * 128 * 512;
      Bb = B + (size_t)bz * 524288 + (size_t)by * 128 * 512;
    } else {  // MODE 4: bz=(n_l, g4); nh = n_l*8 + g*2 + seg
      int n_l = bz >> 2, g = bz & 3;
      int nh = n_l * 8 + g * 2 + seg;
      Ab = A + (size_t)nh * 1048576 + (size_t)bx * 128 * 1024;
      Bb = B + (size_t)nh * 524288 + (size_t)by * 128 * 1024;
    }

    if (NSEG > 1 && seg > 0) __syncthreads();  // WAR: staging buf reuse
    STAGE(0, 0);
    int cur = 0;
#pragma unroll 4
    for (int kc = 0; kc < NK; ++kc) {
      __syncthreads();
      if (kc + 1 < NK) STAGE(cur ^ 1, kc + 1);
      bf16x8 af[4], bf_[4];
#pragma unroll
      for (int f = 0; f < 4; ++f) {
        af[f] = *(const bf16x8*)(sb + cur * 8192 +
                                 ((wr * 64 + f * 16 + l15) << 6) + (l4 << 4));
        bf_[f] = *(const bf16x8*)(sb + 16384 + cur * 8192 +
                                  ((wc * 64 + f * 16 + l15) << 6) + (l4 << 4));
      }
#pragma unroll
      for (int mf = 0; mf < 4; ++mf)
#pragma unroll
        for (int nf = 0; nf < 4; ++nf)
          acc[mf][nf] = __builtin_amdgcn_mfma_f32_16x16x32_bf16(
              af[mf], bf_[nf], acc[mf][nf], 0, 0, 0);
      cur ^= 1;
    }
  }
#undef STAGE

  // ---- epilogue: full-tile LDS repack -> coalesced 16B stores ----
  const int r0 = l4 * 4;
  const int c0 = l15;

  if constexpr (MODE != 5) {
    const bool transp = (MODE == 6) && (bz == 0);  // VT tile
    const float* bias =
        (MODE == 6) ? ((bz == 0) ? bi0 : (bz == 1) ? bi1 : bi2) : nullptr;
    const float bscale = (MODE == 6 && bz == 2) ? RS : 1.0f;
    __syncthreads();  // staging reads done; reuse smem as Cs[128][136]
#pragma unroll
    for (int nf = 0; nf < 4; ++nf) {
      int c_loc = wc * 64 + nf * 16 + c0;
      int c_ = by * 128 + c_loc;
      float bvl = (MODE == 6) ? bias[c_] * bscale : 0.f;
#pragma unroll
      for (int mf = 0; mf < 4; ++mf) {
#pragma unroll
        for (int r = 0; r < 4; ++r) {
          int r_loc = wr * 64 + mf * 16 + r0 + r;
          float v = acc[mf][nf][r] + bvl;
          unsigned short bb;
          if constexpr (MODE == 2) {
            int r_ = bx * 128 + r_loc;  // q index
            unsigned mw = mbits[((size_t)(n0 + (bz >> 3)) * 1024 + r_) * 32 +
                                (c_ >> 5)];
            bb = ((mw >> (c_ & 31)) & 1u) ? f2b(v) : (unsigned short)0;
          } else {
            bb = f2b(v);
          }
          if (transp)
            smem[c_loc * 136 + r_loc] = (short)bb;
          else
            smem[r_loc * 136 + c_loc] = (short)bb;
        }
      }
    }
    __syncthreads();
#pragma unroll
    for (int ch = 0; ch < 8; ++ch) {
      int idx = ch * 256 + tid;
      int row = idx >> 4;
      int col = (idx & 15) << 3;
      bf16x8 v = *(const bf16x8*)(smem + row * 136 + col);
      if constexpr (MODE == 2) {  // P[z][q][l]
        int r_ = bx * 128 + row, cB = by * 128 + col;
        *(bf16x8*)(outb + (size_t)bz * 1048576 + (size_t)r_ * 1024 + cB) = v;
      } else if constexpr (MODE == 4) {  // Ah[z][q][e]
        int r_ = bx * 128 + row, cB = by * 128 + col;
        *(bf16x8*)(outb + (size_t)bz * 524288 + (size_t)r_ * 512 + cB) = v;
      } else {  // MODE 6
        unsigned short* O = outb + (size_t)bz * ostr;
        if (bz == 0) {  // VT [nl][h][e][s]; tile rows = e-dim
          int eB = by * 128 + row;
          int r_ = bx * 128 + col;  // s-dim, 8 contiguous
          int nl = r_ >> 10, s = r_ & 1023, h = eB >> 9, e = eB & 511;
          *(bf16x8*)(O + (((size_t)nl * 8 + h) * 512 + e) * 1024 + s) = v;
        } else {  // K/Q [nl][h][s][e]
          int r_ = bx * 128 + row, cB = by * 128 + col;
          int nl = r_ >> 10, s = r_ & 1023, h = cB >> 9, e = cB & 511;
          *(bf16x8*)(O + (((size_t)nl * 8 + h) * 1024 + s) * 512 + e) = v;
        }
      }
    }
  } else {
    // MODE 5: fp32 tile, two 64-row passes via Cs32[64][136]
    float* const Cs32 = (float*)smem;
#pragma unroll
    for (int hh = 0; hh < 2; ++hh) {
      __syncthreads();
      if (wr == hh) {
#pragma unroll
        for (int nf = 0; nf < 4; ++nf) {
          int c_loc = wc * 64 + nf * 16 + c0;
          float bvl = bi0[by * 128 + c_loc];
#pragma unroll
          for (int mf = 0; mf < 4; ++mf)
#pragma unroll
            for (int r = 0; r < 4; ++r)
              Cs32[(mf * 16 + r0 + r) * 136 + c_loc] = acc[mf][nf][r] + bvl;
        }
      }
      __syncthreads();
#pragma unroll
      for (int ch = 0; ch < 8; ++ch) {
        int idx = ch * 256 + tid;
        int row = idx >> 5;
        int col = (idx & 31) << 2;
        float4 v = *(const float4*)(Cs32 + row * 136 + col);
        *(float4*)(outf + (size_t)(bx * 128 + hh * 64 + row) * 512 +
                   by * 128 + col) = v;
      }
    }
  }
}

extern "C" void kernel_launch(void* const* d_in, const int* in_sizes, int n_in,
                              void* d_out, int out_size, void* d_ws,
                              size_t ws_size, hipStream_t stream) {
  const float* values = (const float*)d_in[0];
  const float* keys = (const float*)d_in[1];
  const float* query = (const float*)d_in[2];
  const int* maskI = (const int*)d_in[4];
  const float* Wv = (const float*)d_in[5];
  const float* bv = (const float*)d_in[6];
  const float* Wk = (const float*)d_in[7];
  const float* bk = (const float*)d_in[8];
  const float* Wq = (const float*)d_in[9];
  const float* bq = (const float*)d_in[10];
  const float* Wo = (const float*)d_in[11];
  const float* bo = (const float*)d_in[12];
  float* dout = (float*)d_out;

  const int exp_sizes[13] = {4194304, 4194304, 4194304, 1024, 8388608,
                             2097152, 4096,    2097152, 4096, 2097152,
                             4096,    262144,  512};
  bool ok = (n_in == 13);
  if (ok)
    for (int i = 0; i < 13; ++i)
      if (in_sizes[i] != exp_sizes[i]) ok = false;
  if (!ok) {
    k_fill<<<512, 256, 0, stream>>>(dout, out_size, 1000.f);
    return;
  }

  // ---- workspace (BYTES): W | Wo | Ahb(32 slices) | mbits | VT | K | Q | P
  const size_t SZT2 = 16777216, SZT4 = 33554432;
  const size_t fixed = 12582912 + 524288 + 33554432 + 1048576;  // 47,710,208
  const size_t need2 = fixed + 5 * SZT2;  // 131,596,288
  const size_t need4 = fixed + 5 * SZT4;  // 215,482,368 <= proven 222,822,400
  const int NL = (ws_size >= need4) ? 4 : 2;
  if (ws_size < need2) {
    k_fill<<<512, 256, 0, stream>>>(dout, out_size, 2000.f);
    return;
  }
  const size_t SZT = (size_t)NL * 8388608;

  char* w = (char*)d_ws;
  unsigned short* Wvb = (unsigned short*)(w);             // 3 x 4,194,304
  unsigned short* Wob = (unsigned short*)(w + 12582912);  //     524,288
  unsigned short* Ahb = (unsigned short*)(w + 13107200);  //  33,554,432
  unsigned* mbits = (unsigned*)(w + 46661632);            //   1,048,576
  unsigned short* VTb = (unsigned short*)(w + 47710208);
  unsigned short* Kb = (unsigned short*)(w + 47710208 + SZT);
  unsigned short* Qb = (unsigned short*)(w + 47710208 + 2 * SZT);
  unsigned short* Pb = (unsigned short*)(w + 47710208 + 3 * SZT);
  unsigned short* Xc = (unsigned short*)Pb;  // alias: dead before energy

  k_convw4<<<dim3(512, 1, 4), 256, 0, stream>>>(
      (const float4*)Wv, (const float4*)Wk, (const float4*)Wq,
      (const float4*)Wo, (ushort4*)Wvb, (ushort4*)Wob);
  k_maskbits<<<1024, 256, 0, stream>>>(maskI, mbits);

  const int xstr = NL * 524288;   // elems per tensor slice in Xc
  const int ostr = NL * 4194304;  // elems per output tensor (VT/K/Q)

  for (int it = 0; it < 8 / NL; ++it) {
    const int n0 = it * NL;
    const size_t xoff = (size_t)n0 * 524288;
    k_conv3<<<dim3(512 * NL, 1, 3), 256, 0, stream>>>(
        (const float4*)(values + xoff), (const float4*)(keys + xoff),
        (const float4*)(query + xoff), (ushort4*)Xc, NL * 131072, NL * 131072);
    // proj3: M=NL*1024, N=4096, K=512; z: 0=VT,1=K,2=Q
    k_gemm<6><<<dim3(NL * 8, 32, 3), 256, 0, stream>>>(
        Xc, Wvb, bv, bk, bq, nullptr, VTb, nullptr, 0, xstr, ostr);
    // energy: z-major slices (XCD-pinned)
    k_gemm<2><<<dim3(NL * 8, 8, 8), 256, 0, stream>>>(
        Qb, Kb, nullptr, nullptr, nullptr, mbits, Pb, nullptr, n0, 0, 0);
    // PV: z=(n_l,g4), 2-head in-reg sum, K=2x1024 -> Ah[(n0+n_l)*4+g]
    k_gemm<4><<<dim3(NL * 4, 8, 4), 256, 0, stream>>>(
        Pb, VTb, nullptr, nullptr, nullptr, nullptr,
        Ahb + (size_t)n0 * 2097152, nullptr, 0, 0, 0);
  }

  // ---- final: NSEG=4 head-group sum, [8192][512] @ Wo^T + bo -> fp32 ----
  k_gemm<5><<<dim3(64, 4, 1), 256, 0, stream>>>(
      Ahb, Wob, bo, nullptr, nullptr, nullptr, nullptr, dout, 0, 0, 0);
}

// Round 21
// 476.306 us; speedup vs baseline: 1.6023x; 1.0274x over previous
//
#include <hip/hip_runtime.h>

// ---------------------------------------------------------------------------
// ROUND 21: exact revert to r18 (best measured: 479us, absmax 0.25).
// r20's head-sum fold made the final GEMM 90us (serial NSEG=4, 256 blocks)
// for -25us of reduces: net loss. This restores: PV NSEG=2 -> Ah partials ->
// k_reduce4 -> Atb -> final K=512.
// Pipeline: convw4 | maskbits | per-NL-iter { conv3, proj3(MODE 6),
// energy(MODE 2, bitmask, z-major), PV(MODE 4, NSEG=2, z-major), reduce4 }
// | final(MODE 5). Core: 128x128 tile, dbuf GLD16 staging, 1 barrier/K-step,
// full-tile LDS repack epilogue. All index maps validated rounds 8-10.
// ---------------------------------------------------------------------------

#define RS 0.04419417382415922f  // 1/sqrt(512)

typedef __attribute__((ext_vector_type(8))) short bf16x8;
typedef __attribute__((ext_vector_type(4))) float f32x4;

__device__ __forceinline__ unsigned short f2b(float f) {
  unsigned u = __builtin_bit_cast(unsigned, f);
  unsigned r = (u + 0x7FFFu + ((u >> 16) & 1u)) >> 16;  // RNE
  return (unsigned short)r;
}
__device__ __forceinline__ float b2f(unsigned short h) {
  return __builtin_bit_cast(float, ((unsigned)h) << 16);
}

__global__ void k_fill(float* p, int n, float v) {
  int i = blockIdx.x * blockDim.x + threadIdx.x;
  int stride = gridDim.x * blockDim.x;
  for (; i < n; i += stride) p[i] = v;
}

__global__ void k_maskbits(const int* __restrict__ m,
                           unsigned* __restrict__ bits) {
  int wi = blockIdx.x * 256 + threadIdx.x;
  const int* src = m + (size_t)wi * 32;
  unsigned b = 0;
#pragma unroll
  for (int i = 0; i < 32; ++i) b |= (src[i] != 0 ? 1u : 0u) << i;
  bits[wi] = b;
}

// all 4 weight tensors in one dispatch; z: 0=Wv,1=Wk,2=Wq(xRS),3=Wo
__global__ void k_convw4(const float4* __restrict__ wv,
                         const float4* __restrict__ wk,
                         const float4* __restrict__ wq,
                         const float4* __restrict__ wo,
                         ushort4* __restrict__ dqkv, ushort4* __restrict__ dwo) {
  int z = blockIdx.z;
  const float4* s = (z == 0) ? wv : (z == 1) ? wk : (z == 2) ? wq : wo;
  ushort4* d = (z == 3) ? dwo : dqkv + (size_t)z * 524288;
  int n4 = (z == 3) ? 65536 : 524288;
  float scale = (z == 2) ? RS : 1.0f;
  int stride = gridDim.x * blockDim.x;
  for (int i = blockIdx.x * blockDim.x + threadIdx.x; i < n4; i += stride) {
    float4 v = s[i];
    ushort4 o;
    o.x = f2b(v.x * scale); o.y = f2b(v.y * scale);
    o.z = f2b(v.z * scale); o.w = f2b(v.w * scale);
    d[i] = o;
  }
}

// conv fp32->bf16 for v/k/q slices in one dispatch (z selects tensor).
__global__ void k_conv3(const float4* __restrict__ v,
                        const float4* __restrict__ k,
                        const float4* __restrict__ q, ushort4* __restrict__ d,
                        int n4, int dstride) {
  const float4* s = (blockIdx.z == 0) ? v : (blockIdx.z == 1) ? k : q;
  ushort4* dz = d + (size_t)blockIdx.z * dstride;
  int stride = gridDim.x * blockDim.x;
  for (int i = blockIdx.x * blockDim.x + threadIdx.x; i < n4; i += stride) {
    float4 x = s[i];
    ushort4 o;
    o.x = f2b(x.x); o.y = f2b(x.y); o.z = f2b(x.z); o.w = f2b(x.w);
    dz[i] = o;
  }
}

// Sum 4 group-partials per n: a=[NL*4][1024][512] -> o[NL][1024*512]
__global__ void k_reduce4(const unsigned short* __restrict__ a,
                          unsigned short* __restrict__ o, int total) {
  int i = blockIdx.x * blockDim.x + threadIdx.x;
  if (i >= total) return;
  int nl = i >> 17, j = i & 131071;
  const ushort4* av = (const ushort4*)a + (size_t)nl * 524288;
  float4 s = {0.f, 0.f, 0.f, 0.f};
#pragma unroll
  for (int g = 0; g < 4; ++g) {
    ushort4 v = av[g * 131072 + j];
    s.x += b2f(v.x); s.y += b2f(v.y); s.z += b2f(v.z); s.w += b2f(v.w);
  }
  ushort4 r;
  r.x = f2b(s.x); r.y = f2b(s.y); r.z = f2b(s.z); r.w = f2b(s.w);
  ((ushort4*)o)[i] = r;
}

#define GLD16(gp, sp)                                              \
  __builtin_amdgcn_global_load_lds(                                \
      (const __attribute__((address_space(1))) void*)(gp),         \
      (__attribute__((address_space(3))) void*)(sp), 16, 0, 0)

// 128x128-tile GEMM, dbuf GLD16 staging, 1 barrier/K-step, full-tile
// LDS-repacked epilogue. smem = 17408 shorts (34.8KB).
// MODE 2: energy->P[z][q][l], bitmask; z-major (bz=blockIdx.x).
// MODE 4: PV 2-head in-reg sum -> Ah[z][q][e]; z=(n,g4), z-major, K=2x1024.
// MODE 5: final->fp32 (+bias bi0). MODE 6: proj3 (z: 0=VT,1=K,2=Q).
template <int MODE>
__global__ __launch_bounds__(256) void k_gemm(
    const unsigned short* __restrict__ A, const unsigned short* __restrict__ B,
    const float* __restrict__ bi0, const float* __restrict__ bi1,
    const float* __restrict__ bi2, const unsigned* __restrict__ mbits,
    unsigned short* __restrict__ outb, float* __restrict__ outf, int n0,
    int xstr, int ostr) {
  __shared__ short smem[17408];
  char* const sb = (char*)smem;

  const int tid = threadIdx.x;
  const int wid = tid >> 6;
  const int lane = tid & 63;
  const int wr = wid >> 1, wc = wid & 1;
  const int l15 = lane & 15, l4 = lane >> 4;

  int bx, by, bz;
  if constexpr (MODE == 2 || MODE == 4) {  // z-major: XCD-pinned slices
    bz = blockIdx.x; bx = blockIdx.y; by = blockIdx.z;
  } else {
    bx = blockIdx.x; by = blockIdx.y; bz = blockIdx.z;
  }

  constexpr int KSEG = (MODE == 4) ? 1024 : 512;
  constexpr int NK = KSEG / 32;
  constexpr int NSEG = (MODE == 4) ? 2 : 1;

  f32x4 acc[4][4];
#pragma unroll
  for (int i = 0; i < 4; ++i)
#pragma unroll
    for (int j = 0; j < 4; ++j) acc[i][j] = (f32x4){0.f, 0.f, 0.f, 0.f};

  const unsigned short* Ab;
  const unsigned short* Bb;

#define STAGE(buf, kc)                                             \
  {                                                                \
    _Pragma("unroll") for (int is = 0; is < 2; ++is) {             \
      int c = is * 256 + tid;                                      \
      int row = c >> 2, col = (c & 3) << 3;                        \
      GLD16(Ab + (size_t)row * KSEG + (kc)*32 + col,               \
            sb + (buf)*8192 + is * 4096 + wid * 1024);             \
      GLD16(Bb + (size_t)row * KSEG + (kc)*32 + col,               \
            sb + 16384 + (buf)*8192 + is * 4096 + wid * 1024);     \
    }                                                              \
  }

  for (int seg = 0; seg < NSEG; ++seg) {
    if constexpr (MODE == 5) {
      Ab = A + (size_t)bx * 128 * 512;
      Bb = B + (size_t)by * 128 * 512;
    } else if constexpr (MODE == 6) {
      Ab = A + (size_t)bz * xstr + (size_t)bx * 128 * 512;
      Bb = B + (size_t)bz * 2097152 + (size_t)by * 128 * 512;
    } else if constexpr (MODE == 2) {
      Ab = A + (size_t)bz * 524288 + (size_t)bx * 128 * 512;
      Bb = B + (size_t)bz * 524288 + (size_t)by * 128 * 512;
    } else {  // MODE 4: bz=(n_l, g4); nh = n_l*8 + g*2 + seg
      int n_l = bz >> 2, g = bz & 3;
      int nh = n_l * 8 + g * 2 + seg;
      Ab = A + (size_t)nh * 1048576 + (size_t)bx * 128 * 1024;
      Bb = B + (size_t)nh * 524288 + (size_t)by * 128 * 1024;
    }

    if (NSEG > 1 && seg > 0) __syncthreads();  // WAR: staging buf reuse
    STAGE(0, 0);
    int cur = 0;
#pragma unroll 4
    for (int kc = 0; kc < NK; ++kc) {
      __syncthreads();
      if (kc + 1 < NK) STAGE(cur ^ 1, kc + 1);
      bf16x8 af[4], bf_[4];
#pragma unroll
      for (int f = 0; f < 4; ++f) {
        af[f] = *(const bf16x8*)(sb + cur * 8192 +
                                 ((wr * 64 + f * 16 + l15) << 6) + (l4 << 4));
        bf_[f] = *(const bf16x8*)(sb + 16384 + cur * 8192 +
                                  ((wc * 64 + f * 16 + l15) << 6) + (l4 << 4));
      }
#pragma unroll
      for (int mf = 0; mf < 4; ++mf)
#pragma unroll
        for (int nf = 0; nf < 4; ++nf)
          acc[mf][nf] = __builtin_amdgcn_mfma_f32_16x16x32_bf16(
              af[mf], bf_[nf], acc[mf][nf], 0, 0, 0);
      cur ^= 1;
    }
  }
#undef STAGE

  // ---- epilogue: full-tile LDS repack -> coalesced 16B stores ----
  const int r0 = l4 * 4;
  const int c0 = l15;

  if constexpr (MODE != 5) {
    const bool transp = (MODE == 6) && (bz == 0);  // VT tile
    const float* bias =
        (MODE == 6) ? ((bz == 0) ? bi0 : (bz == 1) ? bi1 : bi2) : nullptr;
    const float bscale = (MODE == 6 && bz == 2) ? RS : 1.0f;
    __syncthreads();  // staging reads done; reuse smem as Cs[128][136]
#pragma unroll
    for (int nf = 0; nf < 4; ++nf) {
      int c_loc = wc * 64 + nf * 16 + c0;
      int c_ = by * 128 + c_loc;
      float bvl = (MODE == 6) ? bias[c_] * bscale : 0.f;
#pragma unroll
      for (int mf = 0; mf < 4; ++mf) {
#pragma unroll
        for (int r = 0; r < 4; ++r) {
          int r_loc = wr * 64 + mf * 16 + r0 + r;
          float v = acc[mf][nf][r] + bvl;
          unsigned short bb;
          if constexpr (MODE == 2) {
            int r_ = bx * 128 + r_loc;  // q index
            unsigned mw = mbits[((size_t)(n0 + (bz >> 3)) * 1024 + r_) * 32 +
                                (c_ >> 5)];
            bb = ((mw >> (c_ & 31)) & 1u) ? f2b(v) : (unsigned short)0;
          } else {
            bb = f2b(v);
          }
          if (transp)
            smem[c_loc * 136 + r_loc] = (short)bb;
          else
            smem[r_loc * 136 + c_loc] = (short)bb;
        }
      }
    }
    __syncthreads();
#pragma unroll
    for (int ch = 0; ch < 8; ++ch) {
      int idx = ch * 256 + tid;
      int row = idx >> 4;
      int col = (idx & 15) << 3;
      bf16x8 v = *(const bf16x8*)(smem + row * 136 + col);
      if constexpr (MODE == 2) {  // P[z][q][l]
        int r_ = bx * 128 + row, cB = by * 128 + col;
        *(bf16x8*)(outb + (size_t)bz * 1048576 + (size_t)r_ * 1024 + cB) = v;
      } else if constexpr (MODE == 4) {  // Ah[z][q][e]
        int r_ = bx * 128 + row, cB = by * 128 + col;
        *(bf16x8*)(outb + (size_t)bz * 524288 + (size_t)r_ * 512 + cB) = v;
      } else {  // MODE 6
        unsigned short* O = outb + (size_t)bz * ostr;
        if (bz == 0) {  // VT [nl][h][e][s]; tile rows = e-dim
          int eB = by * 128 + row;
          int r_ = bx * 128 + col;  // s-dim, 8 contiguous
          int nl = r_ >> 10, s = r_ & 1023, h = eB >> 9, e = eB & 511;
          *(bf16x8*)(O + (((size_t)nl * 8 + h) * 512 + e) * 1024 + s) = v;
        } else {  // K/Q [nl][h][s][e]
          int r_ = bx * 128 + row, cB = by * 128 + col;
          int nl = r_ >> 10, s = r_ & 1023, h = cB >> 9, e = cB & 511;
          *(bf16x8*)(O + (((size_t)nl * 8 + h) * 1024 + s) * 512 + e) = v;
        }
      }
    }
  } else {
    // MODE 5: fp32 tile, two 64-row passes via Cs32[64][136]
    float* const Cs32 = (float*)smem;
#pragma unroll
    for (int hh = 0; hh < 2; ++hh) {
      __syncthreads();
      if (wr == hh) {
#pragma unroll
        for (int nf = 0; nf < 4; ++nf) {
          int c_loc = wc * 64 + nf * 16 + c0;
          float bvl = bi0[by * 128 + c_loc];
#pragma unroll
          for (int mf = 0; mf < 4; ++mf)
#pragma unroll
            for (int r = 0; r < 4; ++r)
              Cs32[(mf * 16 + r0 + r) * 136 + c_loc] = acc[mf][nf][r] + bvl;
        }
      }
      __syncthreads();
#pragma unroll
      for (int ch = 0; ch < 8; ++ch) {
        int idx = ch * 256 + tid;
        int row = idx >> 5;
        int col = (idx & 31) << 2;
        float4 v = *(const float4*)(Cs32 + row * 136 + col);
        *(float4*)(outf + (size_t)(bx * 128 + hh * 64 + row) * 512 +
                   by * 128 + col) = v;
      }
    }
  }
}

extern "C" void kernel_launch(void* const* d_in, const int* in_sizes, int n_in,
                              void* d_out, int out_size, void* d_ws,
                              size_t ws_size, hipStream_t stream) {
  const float* values = (const float*)d_in[0];
  const float* keys = (const float*)d_in[1];
  const float* query = (const float*)d_in[2];
  const int* maskI = (const int*)d_in[4];
  const float* Wv = (const float*)d_in[5];
  const float* bv = (const float*)d_in[6];
  const float* Wk = (const float*)d_in[7];
  const float* bk = (const float*)d_in[8];
  const float* Wq = (const float*)d_in[9];
  const float* bq = (const float*)d_in[10];
  const float* Wo = (const float*)d_in[11];
  const float* bo = (const float*)d_in[12];
  float* dout = (float*)d_out;

  const int exp_sizes[13] = {4194304, 4194304, 4194304, 1024, 8388608,
                             2097152, 4096,    2097152, 4096, 2097152,
                             4096,    262144,  512};
  bool ok = (n_in == 13);
  if (ok)
    for (int i = 0; i < 13; ++i)
      if (in_sizes[i] != exp_sizes[i]) ok = false;
  if (!ok) {
    k_fill<<<512, 256, 0, stream>>>(dout, out_size, 1000.f);
    return;
  }

  // ---- workspace (BYTES): W | Wo | Atb | mbits | VT | K | Q | P ----
  const size_t SZT2 = 16777216, SZT4 = 33554432;
  const size_t need2 = 22544384 + 3 * SZT2 + 2 * SZT2;  // 106,430,464
  const size_t need4 = 22544384 + 3 * SZT4 + 2 * SZT4;  // 190,316,544
  const int NL = (ws_size >= need4) ? 4 : 2;
  if (ws_size < need2) {
    k_fill<<<512, 256, 0, stream>>>(dout, out_size, 2000.f);
    return;
  }
  const size_t SZT = (size_t)NL * 8388608;

  char* w = (char*)d_ws;
  unsigned short* Wvb = (unsigned short*)(w);             // 3 x 4,194,304
  unsigned short* Wob = (unsigned short*)(w + 12582912);  //     524,288
  unsigned short* Atb = (unsigned short*)(w + 13107200);  //   8,388,608
  unsigned* mbits = (unsigned*)(w + 21495808);            //   1,048,576
  unsigned short* VTb = (unsigned short*)(w + 22544384);
  unsigned short* Kb = (unsigned short*)(w + 22544384 + SZT);
  unsigned short* Qb = (unsigned short*)(w + 22544384 + 2 * SZT);
  unsigned short* Pb = (unsigned short*)(w + 22544384 + 3 * SZT);
  unsigned short* Xc = (unsigned short*)Pb;   // alias: dead before energy
  unsigned short* Ahb = (unsigned short*)Qb;  // alias: Q dead after energy

  k_convw4<<<dim3(512, 1, 4), 256, 0, stream>>>(
      (const float4*)Wv, (const float4*)Wk, (const float4*)Wq,
      (const float4*)Wo, (ushort4*)Wvb, (ushort4*)Wob);
  k_maskbits<<<1024, 256, 0, stream>>>(maskI, mbits);

  const int xstr = NL * 524288;   // elems per tensor slice in Xc
  const int ostr = NL * 4194304;  // elems per output tensor (VT/K/Q)

  for (int it = 0; it < 8 / NL; ++it) {
    const int n0 = it * NL;
    const size_t xoff = (size_t)n0 * 524288;
    k_conv3<<<dim3(512 * NL, 1, 3), 256, 0, stream>>>(
        (const float4*)(values + xoff), (const float4*)(keys + xoff),
        (const float4*)(query + xoff), (ushort4*)Xc, NL * 131072, NL * 131072);
    // proj3: M=NL*1024, N=4096, K=512; z: 0=VT,1=K,2=Q (default order)
    k_gemm<6><<<dim3(NL * 8, 32, 3), 256, 0, stream>>>(
        Xc, Wvb, bv, bk, bq, nullptr, VTb, nullptr, 0, xstr, ostr);
    // energy: z-major slices (XCD-pinned)
    k_gemm<2><<<dim3(NL * 8, 8, 8), 256, 0, stream>>>(
        Qb, Kb, nullptr, nullptr, nullptr, mbits, Pb, nullptr, n0, 0, 0);
    // PV: z=(n,g4), 2-head in-reg sum, K=2x1024; 512 blocks (2/CU)
    k_gemm<4><<<dim3(NL * 4, 8, 4), 256, 0, stream>>>(
        Pb, VTb, nullptr, nullptr, nullptr, nullptr, Ahb, nullptr, 0, 0, 0);
    // sum 4 group-partials
    k_reduce4<<<NL * 512, 256, 0, stream>>>(Ahb, Atb + (size_t)n0 * 524288,
                                            NL * 131072);
  }

  // ---- final: [8192][512] @ Wo^T + bo -> fp32 d_out ----
  k_gemm<5><<<dim3(64, 4, 1), 256, 0, stream>>>(
      Atb, Wob, bo, nullptr, nullptr, nullptr, nullptr, dout, 0, 0, 0);
}